// Round 1
// 216.175 us; speedup vs baseline: 1.0190x; 1.0190x over previous
//
#include <hip/hip_runtime.h>
#include <hip/hip_bf16.h>

// Problem constants (fixed by the reference: B=4,S=2048,D=1024,E=8,H=1024)
#define T_TOK 8192
#define DDIM  1024
#define NEXP  8
#define HDIM  1024
#define SLOT_CAP 17536   // 137 M-tiles * 128; >= 16384 + 8*127 padding worst case
#define NCBLK 32         // blocks for count/slotfill

typedef short bf16x8 __attribute__((ext_vector_type(8)));   // 8 bf16 in 4 VGPRs
typedef float f32x4  __attribute__((ext_vector_type(4)));
typedef unsigned short u16x8 __attribute__((ext_vector_type(8)));

typedef const __attribute__((address_space(1))) unsigned int* gas_ptr;
typedef __attribute__((address_space(3))) unsigned int*       las_ptr;
#define GLD16(gp, lp) __builtin_amdgcn_global_load_lds((gas_ptr)(gp), (las_ptr)(lp), 16, 0, 0)

// fp32 -> bf16 round-to-nearest-even
static __device__ __forceinline__ unsigned short f2b(float f) {
    union { float f; unsigned int u; } v; v.f = f;
    unsigned int u = v.u;
    u += 0x7fffu + ((u >> 16) & 1u);
    return (unsigned short)(u >> 16);
}
static __device__ __forceinline__ float b2f(unsigned short h) {
    union { unsigned int u; float f; } v; v.u = ((unsigned int)h) << 16;
    return v.f;
}

// ---------------------------------------------------------------------------
// K1: routing. One block per token: fp64 logits (selection-exact vs numpy),
// softmax top-2 renormalized, 2-stage LDS reduction. Fused x -> bf16.
// (Unchanged; absmax stable at 0.03125.)
// ---------------------------------------------------------------------------
__global__ __launch_bounds__(256) void moe_routing(
    const float* __restrict__ x, const float* __restrict__ wg,
    unsigned short* __restrict__ xb,
    int* __restrict__ tok_e, float* __restrict__ tok_g)
{
    __shared__ double red[256 * 9];   // [thread][expert], stride 9 (bank spread)
    __shared__ double part[64];
    __shared__ double lf[NEXP];

    int t   = blockIdx.x;
    int tid = threadIdx.x;

    float4 xv = ((const float4*)(x + (size_t)t * DDIM))[tid];
    ushort4 xs;
    xs.x = f2b(xv.x); xs.y = f2b(xv.y); xs.z = f2b(xv.z); xs.w = f2b(xv.w);
    ((ushort4*)(xb + (size_t)t * DDIM))[tid] = xs;

    double s[NEXP];
    #pragma unroll
    for (int e = 0; e < NEXP; e++) s[e] = 0.0;
    const float* wr = wg + (size_t)tid * 4 * NEXP;
    #pragma unroll
    for (int j = 0; j < 4; j++) {
        double xj = (double)((&xv.x)[j]);
        #pragma unroll
        for (int e = 0; e < NEXP; e++)
            s[e] += xj * (double)wr[j * NEXP + e];
    }
    #pragma unroll
    for (int e = 0; e < NEXP; e++) red[tid * 9 + e] = s[e];
    __syncthreads();

    if (tid < 64) {
        int e = tid >> 3, p = tid & 7;
        double acc = 0.0;
        for (int i = 0; i < 32; i++) acc += red[(i * 8 + p) * 9 + e];
        part[tid] = acc;
    }
    __syncthreads();
    if (tid < NEXP) {
        double acc = 0.0;
        #pragma unroll
        for (int p = 0; p < 8; p++) acc += part[tid * 8 + p];
        lf[tid] = acc;
    }
    __syncthreads();

    if (tid == 0) {
        double l[NEXP];
        #pragma unroll
        for (int e = 0; e < NEXP; e++) l[e] = lf[e];
        int e0 = 0;
        for (int e = 1; e < NEXP; e++) if (l[e] > l[e0]) e0 = e;
        int e1 = (e0 == 0) ? 1 : 0;
        for (int e = 0; e < NEXP; e++) if (e != e0 && l[e] > l[e1]) e1 = e;
        double g0 = 1.0 / (1.0 + exp(l[e1] - l[e0]));
        double g1 = 1.0 - g0;
        tok_e[2*t] = e0; tok_e[2*t+1] = e1;
        tok_g[2*t] = (float)g0; tok_g[2*t+1] = (float)g1;
    }
}

// ---------------------------------------------------------------------------
// K2a: per-block expert histogram -> cnt_part[b][e]. No global atomics, no
// pre-zeroed memory.
// ---------------------------------------------------------------------------
__global__ __launch_bounds__(256) void moe_count(
    const int* __restrict__ tok_e, int* __restrict__ cnt_part)
{
    __shared__ int h[NEXP];
    if (threadIdx.x < NEXP) h[threadIdx.x] = 0;
    __syncthreads();
    int t = blockIdx.x * 256 + threadIdx.x;
    atomicAdd(&h[tok_e[2*t]], 1);
    atomicAdd(&h[tok_e[2*t+1]], 1);
    __syncthreads();
    if (threadIdx.x < NEXP)
        cnt_part[blockIdx.x * NEXP + threadIdx.x] = h[threadIdx.x];
}

// ---------------------------------------------------------------------------
// K2b (R7: replaces offsets+slotfill, kills the 1-block latency bubble and
// the global cursor): each block redundantly reduces cnt_part (256 L2-hot
// ints) to get counts + 128-aligned meta + its own deterministic cross-block
// base per expert (prefix over blocks b < bid). LDS-atomic local ranks as
// before. Block 0 publishes meta/counts for the GEMM. Slot order within an
// expert is arbitrary — only uniqueness matters, and prefix+rank is unique.
// ---------------------------------------------------------------------------
__global__ __launch_bounds__(256) void moe_slotfill(
    const int* __restrict__ tok_e, const int* __restrict__ cnt_part,
    int* __restrict__ meta, int* __restrict__ counts,
    int* __restrict__ slot_token, int* __restrict__ tok_slot)
{
    __shared__ int h[NEXP];
    __shared__ int tots[NEXP], pres[NEXP], base[NEXP];
    int tid = threadIdx.x;
    if (tid < NEXP) h[tid] = 0;
    __syncthreads();
    int t = blockIdx.x * 256 + tid;
    int e0 = tok_e[2*t],     e1 = tok_e[2*t + 1];
    int r0 = atomicAdd(&h[e0], 1);
    int r1 = atomicAdd(&h[e1], 1);
    if (tid < NEXP) {
        int pre = 0, tot = 0;
        for (int b = 0; b < NCBLK; b++) {
            int c = cnt_part[b * NEXP + tid];
            if (b < (int)blockIdx.x) pre += c;
            tot += c;
        }
        tots[tid] = tot; pres[tid] = pre;
    }
    __syncthreads();
    if (tid < NEXP) {
        int off = 0;
        for (int e = 0; e < tid; e++) off += (tots[e] + 127) & ~127;
        base[tid] = off + pres[tid];
        if (blockIdx.x == 0) {
            meta[tid]   = off;
            counts[tid] = tots[tid];
            if (tid == NEXP - 1) meta[NEXP] = off + ((tots[tid] + 127) & ~127);
        }
    }
    __syncthreads();
    int s0 = base[e0] + r0, s1 = base[e1] + r1;
    slot_token[s0] = t;  tok_slot[2*t]     = s0;
    slot_token[s1] = t;  tok_slot[2*t + 1] = s1;
}

// K3: We [E][D][H] fp32 -> Wt [E][H][D] bf16 (transpose for GEMM B loads).
__global__ __launch_bounds__(256) void moe_wtrans(
    const float* __restrict__ we, unsigned short* __restrict__ wt)
{
    __shared__ unsigned short tile[64][65];
    int e  = blockIdx.z;
    int d0 = blockIdx.y * 64;
    int h0 = blockIdx.x * 64;
    int c  = threadIdx.x & 63;
    int r4 = threadIdx.x >> 6;
    #pragma unroll
    for (int i = 0; i < 64; i += 4)
        tile[r4 + i][c] = f2b(we[((size_t)e * DDIM + d0 + r4 + i) * HDIM + h0 + c]);
    __syncthreads();
    #pragma unroll
    for (int i = 0; i < 64; i += 4)
        wt[((size_t)e * HDIM + h0 + r4 + i) * DDIM + d0 + c] = tile[c][r4 + i];
}

// ---------------------------------------------------------------------------
// K4: grouped gather-GEMM. 128x128 tile, 2-barrier K-loop, A triple-buffered
// (gather), B double-buffered (L2-resident). R7 change: XCD-aware bijective
// work remap. HW linear id f = by*8+bx round-robins XCDs => xcd == bx, so
// every XCD streamed ALL of xb (FETCH 95MB vs 32MB ideal). Remap gives each
// XCD a contiguous run of 137 (by,bx) pairs: 8 consecutive wid share one
// A-panel (256KB, L2-hot), and a chunk spans ~17 m-tiles = ~2 experts of B.
// Predicted FETCH ~50-60MB, +8-12% on dur (m192 mechanism: HBM-latency
// relief for the distance-2 A pipeline).
// ---------------------------------------------------------------------------
__global__ __launch_bounds__(256, 4) void moe_gemm(
    const unsigned short* __restrict__ xb,   // [T][D] bf16
    const unsigned short* __restrict__ wt,   // [E][H][D] bf16
    const float* __restrict__ be,            // [E][H]
    const int* __restrict__ slot_token,
    const int* __restrict__ meta,
    const int* __restrict__ counts,
    unsigned short* __restrict__ y_slot)     // [SLOT_CAP][H] bf16
{
    __shared__ __align__(16) unsigned short As[3][128 * 32];   // 24 KB
    __shared__ __align__(16) unsigned short Bs[2][128 * 32];   // 16 KB

    // XCD-aware bijective remap (T1): f in [0, 8*137), xcd = f & 7.
    int f   = blockIdx.y * gridDim.x + blockIdx.x;
    int wid = (f & 7) * gridDim.y + (f >> 3);     // chunk = nblk/8 = gridDim.y
    int m0 = (wid >> 3) * 128;
    if (m0 >= meta[NEXP]) return;
    int n0 = (wid & 7) * 128;

    int e = 0;
    #pragma unroll
    for (int i = 1; i < NEXP; i++) if (m0 >= meta[i]) e = i;
    int lim = meta[e] + counts[e];           // slots >= lim are padding

    int tid  = threadIdx.x;
    int lane = tid & 63, wv = tid >> 6;

    // Staging geometry: wave w owns 16-row chunks 2w,2w+1 of A and B.
    int rA = 32 * wv + (lane >> 2);
    int kc = (((lane & 3) ^ ((rA >> 1) & 3)) * 8);   // swizzled source column
    int sA0 = m0 + rA, sA1 = sA0 + 16;
    int tA0 = (sA0 < lim) ? slot_token[sA0] : 0;
    int tA1 = (sA1 < lim) ? slot_token[sA1] : 0;
    const unsigned short* gA0 = xb + (size_t)tA0 * DDIM + kc;
    const unsigned short* gA1 = xb + (size_t)tA1 * DDIM + kc;
    const unsigned short* gB0 = wt + ((size_t)e * HDIM + n0 + rA) * DDIM + kc;
    const unsigned short* gB1 = gB0 + (size_t)16 * DDIM;
    int c0 = (2 * wv) * 512;
    int c1 = c0 + 512;

    f32x4 acc[4][4];
    #pragma unroll
    for (int i = 0; i < 4; i++)
        #pragma unroll
        for (int j = 0; j < 4; j++) acc[i][j] = (f32x4){0.f, 0.f, 0.f, 0.f};

    int wm = (wv >> 1) * 64, wn = (wv & 1) * 64;
    int l16 = lane & 15, quad = lane >> 4;
    int ff = (l16 >> 1) & 3;
    int rdA[4], rdB[4];
    #pragma unroll
    for (int i = 0; i < 4; i++) {
        rdA[i] = (wm + i * 16 + l16) * 32 + ((quad ^ ff) * 8);
        rdB[i] = (wn + i * 16 + l16) * 32 + ((quad ^ ff) * 8);
    }

#define ISSUE_A(kkv, Ab)                                                      \
    {                                                                         \
        int ko = (kkv) * 32;                                                  \
        GLD16(gA0 + ko, (Ab) + c0);                                           \
        GLD16(gA1 + ko, (Ab) + c1);                                           \
    }
#define ISSUE_B(kkv, Bb)                                                      \
    {                                                                         \
        int ko = (kkv) * 32;                                                  \
        GLD16(gB0 + ko, (Bb) + c0);                                           \
        GLD16(gB1 + ko, (Bb) + c1);                                           \
    }
#define COMPUTE(Ab, Bb)                                                       \
    {                                                                         \
        bf16x8 bfr[4];                                                        \
        _Pragma("unroll")                                                     \
        for (int j = 0; j < 4; j++)                                           \
            bfr[j] = *(const bf16x8*)((Bb) + rdB[j]);                         \
        _Pragma("unroll")                                                     \
        for (int i = 0; i < 4; i++) {                                         \
            bf16x8 af = *(const bf16x8*)((Ab) + rdA[i]);                      \
            _Pragma("unroll")                                                 \
            for (int j = 0; j < 4; j++)                                       \
                acc[i][j] = __builtin_amdgcn_mfma_f32_16x16x32_bf16(          \
                    af, bfr[j], acc[i][j], 0, 0, 0);                          \
        }                                                                     \
    }

    unsigned short *A0 = As[0], *A1 = As[1], *A2 = As[2];
    unsigned short *B0 = Bs[0], *B1 = Bs[1];

    // FIFO: A(0), B(0), A(1)  -> first wait vmcnt(2) covers A0,B0.
    ISSUE_A(0, A0)
    ISSUE_B(0, B0)
    ISSUE_A(1, A1)

    #pragma unroll 1
    for (int kk = 0; kk < 32; ++kk) {
        asm volatile("" ::: "memory");
        if (kk == 31) __builtin_amdgcn_s_waitcnt(0x0F70);  // vmcnt(0) tail
        else          __builtin_amdgcn_s_waitcnt(0x0F72);  // vmcnt(2)
        __builtin_amdgcn_s_barrier();
        asm volatile("" ::: "memory");
        COMPUTE(A0, B0)
        if (kk < 31) ISSUE_B(kk + 1, B1)      // B: distance-1 (L2-resident)
        if (kk < 30) ISSUE_A(kk + 2, A2)      // A: distance-2 (far gather)
        unsigned short* tA = A0; A0 = A1; A1 = A2; A2 = tA;
        unsigned short* tB = B0; B0 = B1; B1 = tB;
    }
#undef ISSUE_A
#undef ISSUE_B
#undef COMPUTE

    // Epilogue: plain bf16 stores to y_slot. C/D layout col=lane&15,
    // row=quad*4+reg (m89/m91). Pad rows skipped (never read by combine).
    #pragma unroll
    for (int i = 0; i < 4; i++) {
        #pragma unroll
        for (int r = 0; r < 4; r++) {
            int slot = m0 + wm + i * 16 + quad * 4 + r;
            if (slot >= lim) continue;
            unsigned short* yp = y_slot + (size_t)slot * HDIM + n0;
            #pragma unroll
            for (int j = 0; j < 4; j++) {
                int col = wn + j * 16 + l16;
                yp[col] = f2b(acc[i][j][r] + be[e * HDIM + n0 + col]);
            }
        }
    }
}

// ---------------------------------------------------------------------------
// K5: combine — out[t] = g0*y[s0] + g1*y[s1]. R7: 2 tokens per block,
// 16B/lane y_slot loads (G13 sweet spot), fully coalesced; overwrites every
// out element (no out memset needed).
// ---------------------------------------------------------------------------
__global__ __launch_bounds__(256) void moe_combine(
    const unsigned short* __restrict__ y_slot,
    const int* __restrict__ tok_slot, const float* __restrict__ tok_g,
    float* __restrict__ out)
{
    int tid  = threadIdx.x;
    int half = tid >> 7;              // 0/1: which token of this block
    int lane = tid & 127;             // 128 lanes x 8 bf16 = 1024 cols
    int t = blockIdx.x * 2 + half;
    int s0 = tok_slot[2 * t], s1 = tok_slot[2 * t + 1];
    float g0 = tok_g[2 * t],  g1 = tok_g[2 * t + 1];
    u16x8 a = ((const u16x8*)(y_slot + (size_t)s0 * HDIM))[lane];
    u16x8 b = ((const u16x8*)(y_slot + (size_t)s1 * HDIM))[lane];
    float4 o0, o1;
    o0.x = g0 * b2f(a[0]) + g1 * b2f(b[0]);
    o0.y = g0 * b2f(a[1]) + g1 * b2f(b[1]);
    o0.z = g0 * b2f(a[2]) + g1 * b2f(b[2]);
    o0.w = g0 * b2f(a[3]) + g1 * b2f(b[3]);
    o1.x = g0 * b2f(a[4]) + g1 * b2f(b[4]);
    o1.y = g0 * b2f(a[5]) + g1 * b2f(b[5]);
    o1.z = g0 * b2f(a[6]) + g1 * b2f(b[6]);
    o1.w = g0 * b2f(a[7]) + g1 * b2f(b[7]);
    float4* op = (float4*)(out + (size_t)t * HDIM) + lane * 2;
    op[0] = o0;
    op[1] = o1;
}

extern "C" void kernel_launch(void* const* d_in, const int* in_sizes, int n_in,
                              void* d_out, int out_size, void* d_ws, size_t ws_size,
                              hipStream_t stream) {
    const float* x  = (const float*)d_in[0];   // [B,S,D] fp32
    const float* wg = (const float*)d_in[1];   // [D,E]
    const float* we = (const float*)d_in[2];   // [E,D,H]
    const float* be = (const float*)d_in[3];   // [E,H]
    float* out = (float*)d_out;

    char* ws = (char*)d_ws;
    size_t o = 0;
    auto alloc = [&](size_t bytes) -> void* {
        void* p = ws + o;
        o = (o + bytes + 255) & ~(size_t)255;
        return p;
    };
    unsigned short* xb   = (unsigned short*)alloc((size_t)T_TOK * DDIM * 2);
    unsigned short* wtb  = (unsigned short*)alloc((size_t)NEXP * HDIM * DDIM * 2);
    unsigned short* ysl  = (unsigned short*)alloc((size_t)SLOT_CAP * HDIM * 2);
    int*   slot_token    = (int*)  alloc((size_t)SLOT_CAP * 4);
    int*   cnt_part      = (int*)  alloc((size_t)NCBLK * NEXP * 4);
    int*   counts        = (int*)  alloc(NEXP * 4);
    int*   meta          = (int*)  alloc((NEXP + 1) * 4);
    int*   tok_e         = (int*)  alloc((size_t)T_TOK * 2 * 4);
    float* tok_g         = (float*)alloc((size_t)T_TOK * 2 * 4);
    int*   tok_slot      = (int*)  alloc((size_t)T_TOK * 2 * 4);

    // 6 graph nodes, no memsets, no global cursor.
    moe_routing<<<T_TOK, 256, 0, stream>>>(x, wg, xb, tok_e, tok_g);
    moe_count<<<NCBLK, 256, 0, stream>>>(tok_e, cnt_part);
    moe_slotfill<<<NCBLK, 256, 0, stream>>>(tok_e, cnt_part, meta, counts,
                                            slot_token, tok_slot);
    moe_wtrans<<<dim3(HDIM / 64, DDIM / 64, NEXP), 256, 0, stream>>>(we, wtb);
    moe_gemm<<<dim3(HDIM / 128, SLOT_CAP / 128), 256, 0, stream>>>(
        xb, wtb, be, slot_token, meta, counts, ysl);
    moe_combine<<<T_TOK / 2, 256, 0, stream>>>(ysl, tok_slot, tok_g, out);
}

// Round 2
// 213.676 us; speedup vs baseline: 1.0310x; 1.0117x over previous
//
#include <hip/hip_runtime.h>
#include <hip/hip_bf16.h>

// Problem constants (fixed by the reference: B=4,S=2048,D=1024,E=8,H=1024)
#define T_TOK 8192
#define DDIM  1024
#define NEXP  8
#define HDIM  1024
#define SLOT_CAP 17536   // 137 M-tiles * 128; >= 16384 + 8*127 padding worst case
#define NCBLK 32         // blocks for count/slotfill

typedef short bf16x8 __attribute__((ext_vector_type(8)));   // 8 bf16 in 4 VGPRs
typedef float f32x4  __attribute__((ext_vector_type(4)));
typedef unsigned short u16x8 __attribute__((ext_vector_type(8)));

typedef const __attribute__((address_space(1))) unsigned int* gas_ptr;
typedef __attribute__((address_space(3))) unsigned int*       las_ptr;
#define GLD16(gp, lp) __builtin_amdgcn_global_load_lds((gas_ptr)(gp), (las_ptr)(lp), 16, 0, 0)

// fp32 -> bf16 round-to-nearest-even
static __device__ __forceinline__ unsigned short f2b(float f) {
    union { float f; unsigned int u; } v; v.f = f;
    unsigned int u = v.u;
    u += 0x7fffu + ((u >> 16) & 1u);
    return (unsigned short)(u >> 16);
}
static __device__ __forceinline__ float b2f(unsigned short h) {
    union { unsigned int u; float f; } v; v.u = ((unsigned int)h) << 16;
    return v.f;
}

// ---------------------------------------------------------------------------
// K1: routing. One block per token: fp64 logits (selection-exact vs numpy),
// softmax top-2 renormalized, 2-stage LDS reduction. Fused x -> bf16.
// (Unchanged; absmax stable at 0.03125.)
// ---------------------------------------------------------------------------
__global__ __launch_bounds__(256) void moe_routing(
    const float* __restrict__ x, const float* __restrict__ wg,
    unsigned short* __restrict__ xb,
    int* __restrict__ tok_e, float* __restrict__ tok_g)
{
    __shared__ double red[256 * 9];   // [thread][expert], stride 9 (bank spread)
    __shared__ double part[64];
    __shared__ double lf[NEXP];

    int t   = blockIdx.x;
    int tid = threadIdx.x;

    float4 xv = ((const float4*)(x + (size_t)t * DDIM))[tid];
    ushort4 xs;
    xs.x = f2b(xv.x); xs.y = f2b(xv.y); xs.z = f2b(xv.z); xs.w = f2b(xv.w);
    ((ushort4*)(xb + (size_t)t * DDIM))[tid] = xs;

    double s[NEXP];
    #pragma unroll
    for (int e = 0; e < NEXP; e++) s[e] = 0.0;
    const float* wr = wg + (size_t)tid * 4 * NEXP;
    #pragma unroll
    for (int j = 0; j < 4; j++) {
        double xj = (double)((&xv.x)[j]);
        #pragma unroll
        for (int e = 0; e < NEXP; e++)
            s[e] += xj * (double)wr[j * NEXP + e];
    }
    #pragma unroll
    for (int e = 0; e < NEXP; e++) red[tid * 9 + e] = s[e];
    __syncthreads();

    if (tid < 64) {
        int e = tid >> 3, p = tid & 7;
        double acc = 0.0;
        for (int i = 0; i < 32; i++) acc += red[(i * 8 + p) * 9 + e];
        part[tid] = acc;
    }
    __syncthreads();
    if (tid < NEXP) {
        double acc = 0.0;
        #pragma unroll
        for (int p = 0; p < 8; p++) acc += part[tid * 8 + p];
        lf[tid] = acc;
    }
    __syncthreads();

    if (tid == 0) {
        double l[NEXP];
        #pragma unroll
        for (int e = 0; e < NEXP; e++) l[e] = lf[e];
        int e0 = 0;
        for (int e = 1; e < NEXP; e++) if (l[e] > l[e0]) e0 = e;
        int e1 = (e0 == 0) ? 1 : 0;
        for (int e = 0; e < NEXP; e++) if (e != e0 && l[e] > l[e1]) e1 = e;
        double g0 = 1.0 / (1.0 + exp(l[e1] - l[e0]));
        double g1 = 1.0 - g0;
        tok_e[2*t] = e0; tok_e[2*t+1] = e1;
        tok_g[2*t] = (float)g0; tok_g[2*t+1] = (float)g1;
    }
}

// ---------------------------------------------------------------------------
// K2a: per-block expert histogram -> cnt_part[b][e]. No global atomics, no
// pre-zeroed memory.
// ---------------------------------------------------------------------------
__global__ __launch_bounds__(256) void moe_count(
    const int* __restrict__ tok_e, int* __restrict__ cnt_part)
{
    __shared__ int h[NEXP];
    if (threadIdx.x < NEXP) h[threadIdx.x] = 0;
    __syncthreads();
    int t = blockIdx.x * 256 + threadIdx.x;
    atomicAdd(&h[tok_e[2*t]], 1);
    atomicAdd(&h[tok_e[2*t+1]], 1);
    __syncthreads();
    if (threadIdx.x < NEXP)
        cnt_part[blockIdx.x * NEXP + threadIdx.x] = h[threadIdx.x];
}

// ---------------------------------------------------------------------------
// K2b: each block redundantly reduces cnt_part (256 L2-hot ints) to get
// counts + 128-aligned meta + its own deterministic cross-block base per
// expert (prefix over blocks b < bid). LDS-atomic local ranks. Block 0
// publishes meta/counts. Slot order within an expert is arbitrary — only
// uniqueness matters, and prefix+rank is unique.
// ---------------------------------------------------------------------------
__global__ __launch_bounds__(256) void moe_slotfill(
    const int* __restrict__ tok_e, const int* __restrict__ cnt_part,
    int* __restrict__ meta, int* __restrict__ counts,
    int* __restrict__ slot_token, int* __restrict__ tok_slot)
{
    __shared__ int h[NEXP];
    __shared__ int tots[NEXP], pres[NEXP], base[NEXP];
    int tid = threadIdx.x;
    if (tid < NEXP) h[tid] = 0;
    __syncthreads();
    int t = blockIdx.x * 256 + tid;
    int e0 = tok_e[2*t],     e1 = tok_e[2*t + 1];
    int r0 = atomicAdd(&h[e0], 1);
    int r1 = atomicAdd(&h[e1], 1);
    if (tid < NEXP) {
        int pre = 0, tot = 0;
        for (int b = 0; b < NCBLK; b++) {
            int c = cnt_part[b * NEXP + tid];
            if (b < (int)blockIdx.x) pre += c;
            tot += c;
        }
        tots[tid] = tot; pres[tid] = pre;
    }
    __syncthreads();
    if (tid < NEXP) {
        int off = 0;
        for (int e = 0; e < tid; e++) off += (tots[e] + 127) & ~127;
        base[tid] = off + pres[tid];
        if (blockIdx.x == 0) {
            meta[tid]   = off;
            counts[tid] = tots[tid];
            if (tid == NEXP - 1) meta[NEXP] = off + ((tots[tid] + 127) & ~127);
        }
    }
    __syncthreads();
    int s0 = base[e0] + r0, s1 = base[e1] + r1;
    slot_token[s0] = t;  tok_slot[2*t]     = s0;
    slot_token[s1] = t;  tok_slot[2*t + 1] = s1;
}

// K3: We [E][D][H] fp32 -> Wt [E][H][D] bf16 (transpose for GEMM B loads).
__global__ __launch_bounds__(256) void moe_wtrans(
    const float* __restrict__ we, unsigned short* __restrict__ wt)
{
    __shared__ unsigned short tile[64][65];
    int e  = blockIdx.z;
    int d0 = blockIdx.y * 64;
    int h0 = blockIdx.x * 64;
    int c  = threadIdx.x & 63;
    int r4 = threadIdx.x >> 6;
    #pragma unroll
    for (int i = 0; i < 64; i += 4)
        tile[r4 + i][c] = f2b(we[((size_t)e * DDIM + d0 + r4 + i) * HDIM + h0 + c]);
    __syncthreads();
    #pragma unroll
    for (int i = 0; i < 64; i += 4)
        wt[((size_t)e * HDIM + h0 + r4 + i) * DDIM + d0 + c] = tile[c][r4 + i];
}

// ---------------------------------------------------------------------------
// K4: grouped gather-GEMM. 128x128 tile, 2-barrier K-loop, XCD-aware remap
// (R7: FETCH 95->39MB, confirmed near-ideal).
// R8: fix the vmcnt FIFO-coupling defect. Old schedule (A 3-buf dist-2,
// B 2-buf dist-1, wait vmcnt(2)): the single FIFO counter meant waiting for
// B(k) (issued 1 step ago) also force-retired A(k+1) -> A's prefetch depth
// collapsed to 1 and steady-state in-flight drained to 2 loads/thread.
// A is a token-gather that misses the XCD-local L2 (routing is arbitrary,
// per-XCD L2s are not shared) -> ~600-900cy L3/HBM latency exposed per step.
// New schedule: A and B both 3-buf, both distance-2, issue (k+2) right
// after the barrier BEFORE compute. Uniform invariant: at step k's wait the
// loads younger than {A(k),B(k)} are exactly step (k-1)'s 4 -> vmcnt(4)
// steady (vmcnt(0) last step); nothing older is force-retired, in-flight
// 4-8 loads/thread. LDS 48KB -> still 3 blocks/CU.
// WAR safety: step k writes slot (k+2)%3 == (k-1)%3; every wave past
// barrier k has consumed its step-(k-1) ds_reads (MFMA operands in regs
// before the wave could reach the barrier).
// ---------------------------------------------------------------------------
__global__ __launch_bounds__(256, 3) void moe_gemm(
    const unsigned short* __restrict__ xb,   // [T][D] bf16
    const unsigned short* __restrict__ wt,   // [E][H][D] bf16
    const float* __restrict__ be,            // [E][H]
    const int* __restrict__ slot_token,
    const int* __restrict__ meta,
    const int* __restrict__ counts,
    unsigned short* __restrict__ y_slot)     // [SLOT_CAP][H] bf16
{
    __shared__ __align__(16) unsigned short As[3][128 * 32];   // 24 KB
    __shared__ __align__(16) unsigned short Bs[3][128 * 32];   // 24 KB

    // XCD-aware bijective remap (T1): f in [0, 8*137), xcd = f & 7.
    int f   = blockIdx.y * gridDim.x + blockIdx.x;
    int wid = (f & 7) * gridDim.y + (f >> 3);     // chunk = nblk/8 = gridDim.y
    int m0 = (wid >> 3) * 128;
    if (m0 >= meta[NEXP]) return;
    int n0 = (wid & 7) * 128;

    int e = 0;
    #pragma unroll
    for (int i = 1; i < NEXP; i++) if (m0 >= meta[i]) e = i;
    int lim = meta[e] + counts[e];           // slots >= lim are padding

    int tid  = threadIdx.x;
    int lane = tid & 63, wv = tid >> 6;

    // Staging geometry: wave w owns 16-row chunks 2w,2w+1 of A and B.
    int rA = 32 * wv + (lane >> 2);
    int kc = (((lane & 3) ^ ((rA >> 1) & 3)) * 8);   // swizzled source column
    int sA0 = m0 + rA, sA1 = sA0 + 16;
    int tA0 = (sA0 < lim) ? slot_token[sA0] : 0;
    int tA1 = (sA1 < lim) ? slot_token[sA1] : 0;
    const unsigned short* gA0 = xb + (size_t)tA0 * DDIM + kc;
    const unsigned short* gA1 = xb + (size_t)tA1 * DDIM + kc;
    const unsigned short* gB0 = wt + ((size_t)e * HDIM + n0 + rA) * DDIM + kc;
    const unsigned short* gB1 = gB0 + (size_t)16 * DDIM;
    int c0 = (2 * wv) * 512;
    int c1 = c0 + 512;

    f32x4 acc[4][4];
    #pragma unroll
    for (int i = 0; i < 4; i++)
        #pragma unroll
        for (int j = 0; j < 4; j++) acc[i][j] = (f32x4){0.f, 0.f, 0.f, 0.f};

    int wm = (wv >> 1) * 64, wn = (wv & 1) * 64;
    int l16 = lane & 15, quad = lane >> 4;
    int ff = (l16 >> 1) & 3;
    int rdA[4], rdB[4];
    #pragma unroll
    for (int i = 0; i < 4; i++) {
        rdA[i] = (wm + i * 16 + l16) * 32 + ((quad ^ ff) * 8);
        rdB[i] = (wn + i * 16 + l16) * 32 + ((quad ^ ff) * 8);
    }

#define ISSUE_A(kkv, Ab)                                                      \
    {                                                                         \
        int ko = (kkv) * 32;                                                  \
        GLD16(gA0 + ko, (Ab) + c0);                                           \
        GLD16(gA1 + ko, (Ab) + c1);                                           \
    }
#define ISSUE_B(kkv, Bb)                                                      \
    {                                                                         \
        int ko = (kkv) * 32;                                                  \
        GLD16(gB0 + ko, (Bb) + c0);                                           \
        GLD16(gB1 + ko, (Bb) + c1);                                           \
    }
#define COMPUTE(Ab, Bb)                                                       \
    {                                                                         \
        bf16x8 bfr[4];                                                        \
        _Pragma("unroll")                                                     \
        for (int j = 0; j < 4; j++)                                           \
            bfr[j] = *(const bf16x8*)((Bb) + rdB[j]);                         \
        _Pragma("unroll")                                                     \
        for (int i = 0; i < 4; i++) {                                         \
            bf16x8 af = *(const bf16x8*)((Ab) + rdA[i]);                      \
            _Pragma("unroll")                                                 \
            for (int j = 0; j < 4; j++)                                       \
                acc[i][j] = __builtin_amdgcn_mfma_f32_16x16x32_bf16(          \
                    af, bfr[j], acc[i][j], 0, 0, 0);                          \
        }                                                                     \
    }

    unsigned short *A0 = As[0], *A1 = As[1], *A2 = As[2];
    unsigned short *B0 = Bs[0], *B1 = Bs[1], *B2 = Bs[2];

    // Prologue FIFO: A(0),B(0),A(1),B(1). Steady wait vmcnt(4) retires
    // everything through step (k-2)'s issues = {A(k),B(k)} exactly.
    ISSUE_A(0, A0)
    ISSUE_B(0, B0)
    ISSUE_A(1, A1)
    ISSUE_B(1, B1)

    #pragma unroll 1
    for (int kk = 0; kk < 32; ++kk) {
        asm volatile("" ::: "memory");
        if (kk == 31) __builtin_amdgcn_s_waitcnt(0x0F70);  // vmcnt(0) tail
        else          __builtin_amdgcn_s_waitcnt(0x0F74);  // vmcnt(4)
        __builtin_amdgcn_s_barrier();
        asm volatile("" ::: "memory");
        if (kk < 30) {                        // issue BEFORE compute: loads
            ISSUE_B(kk + 2, B2)               // fly under the MFMA phase too
            ISSUE_A(kk + 2, A2)
        }
        COMPUTE(A0, B0)
        unsigned short* tA = A0; A0 = A1; A1 = A2; A2 = tA;
        unsigned short* tB = B0; B0 = B1; B1 = tB; tB = B1; // rotate B 3-way
        B1 = B2; B2 = tB;
    }
#undef ISSUE_A
#undef ISSUE_B
#undef COMPUTE

    // Epilogue: plain bf16 stores to y_slot. C/D layout col=lane&15,
    // row=quad*4+reg (m89/m91). Pad rows skipped (never read by combine).
    #pragma unroll
    for (int i = 0; i < 4; i++) {
        #pragma unroll
        for (int r = 0; r < 4; r++) {
            int slot = m0 + wm + i * 16 + quad * 4 + r;
            if (slot >= lim) continue;
            unsigned short* yp = y_slot + (size_t)slot * HDIM + n0;
            #pragma unroll
            for (int j = 0; j < 4; j++) {
                int col = wn + j * 16 + l16;
                yp[col] = f2b(acc[i][j][r] + be[e * HDIM + n0 + col]);
            }
        }
    }
}

// ---------------------------------------------------------------------------
// K5: combine — out[t] = g0*y[s0] + g1*y[s1]. 2 tokens per block, 16B/lane
// y_slot loads, fully coalesced; overwrites every out element.
// ---------------------------------------------------------------------------
__global__ __launch_bounds__(256) void moe_combine(
    const unsigned short* __restrict__ y_slot,
    const int* __restrict__ tok_slot, const float* __restrict__ tok_g,
    float* __restrict__ out)
{
    int tid  = threadIdx.x;
    int half = tid >> 7;              // 0/1: which token of this block
    int lane = tid & 127;             // 128 lanes x 8 bf16 = 1024 cols
    int t = blockIdx.x * 2 + half;
    int s0 = tok_slot[2 * t], s1 = tok_slot[2 * t + 1];
    float g0 = tok_g[2 * t],  g1 = tok_g[2 * t + 1];
    u16x8 a = ((const u16x8*)(y_slot + (size_t)s0 * HDIM))[lane];
    u16x8 b = ((const u16x8*)(y_slot + (size_t)s1 * HDIM))[lane];
    float4 o0, o1;
    o0.x = g0 * b2f(a[0]) + g1 * b2f(b[0]);
    o0.y = g0 * b2f(a[1]) + g1 * b2f(b[1]);
    o0.z = g0 * b2f(a[2]) + g1 * b2f(b[2]);
    o0.w = g0 * b2f(a[3]) + g1 * b2f(b[3]);
    o1.x = g0 * b2f(a[4]) + g1 * b2f(b[4]);
    o1.y = g0 * b2f(a[5]) + g1 * b2f(b[5]);
    o1.z = g0 * b2f(a[6]) + g1 * b2f(b[6]);
    o1.w = g0 * b2f(a[7]) + g1 * b2f(b[7]);
    float4* op = (float4*)(out + (size_t)t * HDIM) + lane * 2;
    op[0] = o0;
    op[1] = o1;
}

extern "C" void kernel_launch(void* const* d_in, const int* in_sizes, int n_in,
                              void* d_out, int out_size, void* d_ws, size_t ws_size,
                              hipStream_t stream) {
    const float* x  = (const float*)d_in[0];   // [B,S,D] fp32
    const float* wg = (const float*)d_in[1];   // [D,E]
    const float* we = (const float*)d_in[2];   // [E,D,H]
    const float* be = (const float*)d_in[3];   // [E,H]
    float* out = (float*)d_out;

    char* ws = (char*)d_ws;
    size_t o = 0;
    auto alloc = [&](size_t bytes) -> void* {
        void* p = ws + o;
        o = (o + bytes + 255) & ~(size_t)255;
        return p;
    };
    unsigned short* xb   = (unsigned short*)alloc((size_t)T_TOK * DDIM * 2);
    unsigned short* wtb  = (unsigned short*)alloc((size_t)NEXP * HDIM * DDIM * 2);
    unsigned short* ysl  = (unsigned short*)alloc((size_t)SLOT_CAP * HDIM * 2);
    int*   slot_token    = (int*)  alloc((size_t)SLOT_CAP * 4);
    int*   cnt_part      = (int*)  alloc((size_t)NCBLK * NEXP * 4);
    int*   counts        = (int*)  alloc(NEXP * 4);
    int*   meta          = (int*)  alloc((NEXP + 1) * 4);
    int*   tok_e         = (int*)  alloc((size_t)T_TOK * 2 * 4);
    float* tok_g         = (float*)alloc((size_t)T_TOK * 2 * 4);
    int*   tok_slot      = (int*)  alloc((size_t)T_TOK * 2 * 4);

    // 6 graph nodes, no memsets, no global cursor.
    moe_routing<<<T_TOK, 256, 0, stream>>>(x, wg, xb, tok_e, tok_g);
    moe_count<<<NCBLK, 256, 0, stream>>>(tok_e, cnt_part);
    moe_slotfill<<<NCBLK, 256, 0, stream>>>(tok_e, cnt_part, meta, counts,
                                            slot_token, tok_slot);
    moe_wtrans<<<dim3(HDIM / 64, DDIM / 64, NEXP), 256, 0, stream>>>(we, wtb);
    moe_gemm<<<dim3(HDIM / 128, SLOT_CAP / 128), 256, 0, stream>>>(
        xb, wtb, be, slot_token, meta, counts, ysl);
    moe_combine<<<T_TOK / 2, 256, 0, stream>>>(ysl, tok_slot, tok_g, out);
}